// Round 1
// baseline (22140.573 us; speedup 1.0000x reference)
//
#include <hip/hip_runtime.h>
#include <hip/hip_bf16.h>
#include <math.h>

// Problem constants
#define Bc   2
#define Tc   512
#define Cc   768
#define Hc   12
#define HDc  64
#define Vc   50304
#define BTc  (Bc*Tc)          // 1024
#define NHc  (Bc*Hc)          // 24
#define C3   (3*Cc)           // 2304
#define C4   (4*Cc)           // 3072
#define EPS_LN 1e-5f
#define H_STEP 0.05f
#define LOGMARG (-6.2383246250395077847550890931236f)  // -log(512)

// ---------------- block reductions (256 threads = 4 waves of 64) ----------
__device__ __forceinline__ float waveReduceMax(float v) {
    for (int o = 32; o; o >>= 1) v = fmaxf(v, __shfl_down(v, o));
    return v;
}
__device__ __forceinline__ float waveReduceSum(float v) {
    for (int o = 32; o; o >>= 1) v += __shfl_down(v, o);
    return v;
}
__device__ __forceinline__ float blockReduceMax(float v) {
    __shared__ float sm[4];
    v = waveReduceMax(v);
    __syncthreads();
    if ((threadIdx.x & 63) == 0) sm[threadIdx.x >> 6] = v;
    __syncthreads();
    return fmaxf(fmaxf(sm[0], sm[1]), fmaxf(sm[2], sm[3]));
}
__device__ __forceinline__ float blockReduceSum(float v) {
    __shared__ float sm[4];
    v = waveReduceSum(v);
    __syncthreads();
    if ((threadIdx.x & 63) == 0) sm[threadIdx.x >> 6] = v;
    __syncthreads();
    return sm[0] + sm[1] + sm[2] + sm[3];
}

// ---------------- embedding: z = wte[idx] + wpe[t] ------------------------
__global__ __launch_bounds__(256)
void embed_kernel(const int* __restrict__ idx, const float* __restrict__ wte,
                  const float* __restrict__ wpe, float* __restrict__ z)
{
    int i = blockIdx.x * 256 + threadIdx.x;      // 0 .. BT*C-1
    if (i >= BTc * Cc) return;
    int r = i / Cc, c = i - r * Cc;
    int tok = idx[r];
    z[i] = wte[(size_t)tok * Cc + c] + wpe[(size_t)(r & (Tc - 1)) * Cc + c];
}

// ---------------- LayerNorm over 768 dims (+optional time column) ---------
// input row = blockIdx.x*rowMul + rowAdd ; output row = blockIdx.x (stride 768)
__global__ __launch_bounds__(256)
void ln_kernel(const float* __restrict__ X, const float* __restrict__ w,
               const float* __restrict__ bb, float* __restrict__ Y,
               float* __restrict__ yt, int hasT, float tval,
               int rowMul, int rowAdd)
{
    int orow = blockIdx.x;
    int r = orow * rowMul + rowAdd;
    const float* x = X + (size_t)r * Cc;
    int tid = threadIdx.x;
    float xv[3];
#pragma unroll
    for (int q = 0; q < 3; ++q) xv[q] = x[tid + 256 * q];
    float s = xv[0] + xv[1] + xv[2];
    s = blockReduceSum(s);
    float cnt = hasT ? (float)(Cc + 1) : (float)Cc;
    float mu = (s + (hasT ? tval : 0.f)) / cnt;
    float d0 = xv[0] - mu, d1 = xv[1] - mu, d2 = xv[2] - mu;
    float ss = d0 * d0 + d1 * d1 + d2 * d2;
    ss = blockReduceSum(ss);
    float dt = tval - mu;
    float var = (ss + (hasT ? dt * dt : 0.f)) / cnt;
    float rs = rsqrtf(var + EPS_LN);
    float* yrow = Y + (size_t)orow * Cc;
#pragma unroll
    for (int q = 0; q < 3; ++q) {
        int c = tid + 256 * q;
        yrow[c] = (xv[q] - mu) * rs * w[c] + bb[c];
    }
    if (hasT && tid == 0) yt[orow] = dt * rs * w[Cc] + bb[Cc];
}

// ---------------- general tiled fp32 GEMM: C = A[M,K] @ B[K,N] ------------
// EPI: 0 = +bias ; 1 = gelu(+bias) ; 2 = C := C + h*( acc + bias )  (Euler)
// optional rank-1 term extraA[m]*extraB[n] (handles the 769th LN column)
// Requires M%64==0, N%64==0, K%16==0 (true for all uses here).
template <int EPI>
__global__ __launch_bounds__(256)
void gemm_nn(const float* __restrict__ A, int lda,
             const float* __restrict__ Bm, int ldb,
             float* __restrict__ Cm, int ldc,
             int M, int N, int K,
             const float* __restrict__ bias,
             const float* __restrict__ extraA,
             const float* __restrict__ extraB,
             float hstep)
{
    __shared__ float As[16][65];
    __shared__ float Bs[16][65];
    int tid = threadIdx.x;
    int tx = tid & 15, ty = tid >> 4;
    int m0 = blockIdx.y * 64, n0 = blockIdx.x * 64;
    float acc[4][4] = {};
    for (int k0 = 0; k0 < K; k0 += 16) {
#pragma unroll
        for (int l = tid; l < 1024; l += 256) {
            int m = l >> 4, k = l & 15;
            As[k][m] = A[(size_t)(m0 + m) * lda + (k0 + k)];
        }
#pragma unroll
        for (int l = tid; l < 1024; l += 256) {
            int k = l >> 6, n = l & 63;
            Bs[k][n] = Bm[(size_t)(k0 + k) * ldb + (n0 + n)];
        }
        __syncthreads();
#pragma unroll
        for (int kk = 0; kk < 16; ++kk) {
            float a[4], b[4];
#pragma unroll
            for (int i = 0; i < 4; ++i) a[i] = As[kk][ty + 16 * i];
#pragma unroll
            for (int j = 0; j < 4; ++j) b[j] = Bs[kk][tx + 16 * j];
#pragma unroll
            for (int i = 0; i < 4; ++i)
#pragma unroll
                for (int j = 0; j < 4; ++j) acc[i][j] += a[i] * b[j];
        }
        __syncthreads();
    }
#pragma unroll
    for (int i = 0; i < 4; ++i) {
        int m = m0 + ty + 16 * i;
#pragma unroll
        for (int j = 0; j < 4; ++j) {
            int n = n0 + tx + 16 * j;
            float v = acc[i][j];
            if (extraA) v += extraA[m] * extraB[n];
            if (bias) v += bias[n];
            size_t oi = (size_t)m * ldc + n;
            if (EPI == 1) {
                v = 0.5f * v * (1.f + erff(v * 0.70710678118654752440f));
                Cm[oi] = v;
            } else if (EPI == 2) {
                Cm[oi] = Cm[oi] + hstep * v;
            } else {
                Cm[oi] = v;
            }
        }
    }
}

// ---------------- attention scores S = q@k^T / 8, causal tiles ------------
__global__ __launch_bounds__(256)
void qk_kernel(const float* __restrict__ qkv, float* __restrict__ S)
{
    int n = blockIdx.z;                       // 0..23  (b*H + h)
    int ti = blockIdx.y, tj = blockIdx.x;     // 64x64 tiles
    if (tj > ti) return;                      // fully-masked tile
    int b = n / Hc, h = n - b * Hc;
    __shared__ float qs[64][65];
    __shared__ float ks[64][65];
    int tid = threadIdx.x;
    const size_t rowbase = (size_t)(b * Tc) * C3 + h * HDc;
    int i0 = ti * 64, j0 = tj * 64;
    for (int l = tid; l < 4096; l += 256) {
        int r = l >> 6, d = l & 63;
        qs[r][d] = qkv[rowbase + (size_t)(i0 + r) * C3 + d];
        ks[r][d] = qkv[rowbase + (size_t)(j0 + r) * C3 + Cc + d];
    }
    __syncthreads();
    int tx = tid & 15, ty = tid >> 4;
    float acc[4][4] = {};
#pragma unroll 4
    for (int d = 0; d < 64; ++d) {
        float a[4], b4[4];
#pragma unroll
        for (int i = 0; i < 4; ++i) a[i] = qs[ty + 16 * i][d];
#pragma unroll
        for (int j = 0; j < 4; ++j) b4[j] = ks[tx + 16 * j][d];
#pragma unroll
        for (int i = 0; i < 4; ++i)
#pragma unroll
            for (int j = 0; j < 4; ++j) acc[i][j] += a[i] * b4[j];
    }
    float* Sb = S + (size_t)n * Tc * Tc;
#pragma unroll
    for (int i = 0; i < 4; ++i)
#pragma unroll
        for (int j = 0; j < 4; ++j)
            Sb[(size_t)(i0 + ty + 16 * i) * Tc + (j0 + tx + 16 * j)] = acc[i][j] * 0.125f;
}

// ---------------- causal softmax, in place, writes zeros above diag -------
__global__ __launch_bounds__(256)
void softmax_causal(float* __restrict__ S)
{
    int rw = blockIdx.x;              // n*512 + i
    int i = rw & (Tc - 1);
    float* row = S + (size_t)rw * Tc;
    int tid = threadIdx.x;
    int j0 = tid, j1 = tid + 256;
    float x0 = (j0 <= i) ? row[j0] : -INFINITY;
    float x1 = (j1 <= i) ? row[j1] : -INFINITY;
    float mx = blockReduceMax(fmaxf(x0, x1));
    float e0 = (j0 <= i) ? expf(x0 - mx) : 0.f;
    float e1 = (j1 <= i) ? expf(x1 - mx) : 0.f;
    float s = blockReduceSum(e0 + e1);
    float inv = 1.f / s;
    row[j0] = e0 * inv;
    row[j1] = e1 * inv;
}

// ---------------- 512x512 transpose per head ------------------------------
__global__ __launch_bounds__(256)
void transpose512(const float* __restrict__ A, float* __restrict__ At)
{
    __shared__ float tile[32][33];
    int n = blockIdx.z;
    int i0 = blockIdx.y * 32, j0 = blockIdx.x * 32;
    const float* Ab = A + (size_t)n * Tc * Tc;
    float* Atb = At + (size_t)n * Tc * Tc;
    int tx = threadIdx.x & 31, ty = threadIdx.x >> 5;   // 32 x 8
    for (int r = ty; r < 32; r += 8)
        tile[r][tx] = Ab[(size_t)(i0 + r) * Tc + (j0 + tx)];
    __syncthreads();
    for (int r = ty; r < 32; r += 8)
        Atb[(size_t)(j0 + r) * Tc + (i0 + tx)] = tile[tx][r];
}

// ---------------- zero helper ---------------------------------------------
__global__ void zero_kernel(float* __restrict__ p, int n)
{
    int i = blockIdx.x * 256 + threadIdx.x;
    if (i < n) p[i] = 0.f;
}

// ---------------- one Sinkhorn half-iteration -----------------------------
// uout[n,i] = logmarg - LSE_j( -Crow[n,i,j] + vin[n,j] )
__global__ __launch_bounds__(256)
void sink_pass(const float* __restrict__ Cmat, const float* __restrict__ vin,
               float* __restrict__ uout)
{
    int rw = blockIdx.x;                  // n*512 + i
    int n = rw >> 9;
    const float* row = Cmat + (size_t)rw * Tc;
    const float* vv = vin + n * Tc;
    int tid = threadIdx.x;
    float x0 = -row[tid] + vv[tid];
    float x1 = -row[tid + 256] + vv[tid + 256];
    float mx = blockReduceMax(fmaxf(x0, x1));
    float s = blockReduceSum(expf(x0 - mx) + expf(x1 - mx));
    if (tid == 0) uout[rw] = LOGMARG - (mx + logf(s));
}

// ---------------- pi = exp(-C + u_i + v_j) * T ----------------------------
__global__ __launch_bounds__(256)
void pi_kernel(const float* __restrict__ Cmat, const float* __restrict__ u,
               const float* __restrict__ v, float* __restrict__ pi)
{
    int idx = blockIdx.x * 256 + threadIdx.x;     // 24*512*512 total
    int j = idx & (Tc - 1);
    int i = (idx >> 9) & (Tc - 1);
    int n = idx >> 18;
    pi[idx] = expf(-Cmat[idx] + u[n * Tc + i] + v[n * Tc + j]) * (float)Tc;
}

// ---------------- y = pi @ v  (per head), write merged heads --------------
__global__ __launch_bounds__(256)
void piv_kernel(const float* __restrict__ pi, const float* __restrict__ qkv,
                float* __restrict__ y)
{
    int n = blockIdx.y;          // head-batch
    int m0 = blockIdx.x * 64;    // row tile
    int b = n / Hc, h = n - b * Hc;
    __shared__ float Ps[16][65];
    __shared__ float Vs[16][65];
    const float* Pb = pi + (size_t)n * Tc * Tc;
    const size_t vbase = (size_t)(b * Tc) * C3 + 2 * Cc + h * HDc;
    int tid = threadIdx.x, tx = tid & 15, ty = tid >> 4;
    float acc[4][4] = {};
    for (int k0 = 0; k0 < Tc; k0 += 16) {
#pragma unroll
        for (int l = tid; l < 1024; l += 256) {
            int m = l >> 4, k = l & 15;
            Ps[k][m] = Pb[(size_t)(m0 + m) * Tc + (k0 + k)];
        }
#pragma unroll
        for (int l = tid; l < 1024; l += 256) {
            int k = l >> 6, d = l & 63;
            Vs[k][d] = qkv[vbase + (size_t)(k0 + k) * C3 + d];
        }
        __syncthreads();
#pragma unroll
        for (int kk = 0; kk < 16; ++kk) {
            float a[4], b4[4];
#pragma unroll
            for (int i = 0; i < 4; ++i) a[i] = Ps[kk][ty + 16 * i];
#pragma unroll
            for (int j = 0; j < 4; ++j) b4[j] = Vs[kk][tx + 16 * j];
#pragma unroll
            for (int i = 0; i < 4; ++i)
#pragma unroll
                for (int j = 0; j < 4; ++j) acc[i][j] += a[i] * b4[j];
        }
        __syncthreads();
    }
#pragma unroll
    for (int i = 0; i < 4; ++i)
#pragma unroll
        for (int j = 0; j < 4; ++j)
            y[(size_t)(b * Tc + m0 + ty + 16 * i) * Cc + h * HDc + tx + 16 * j] = acc[i][j];
}

// ---------------- logits: out[b,v] = xf[b,:] . wte[v,:] -------------------
__global__ __launch_bounds__(256)
void logits_kernel(const float* __restrict__ xf, const float* __restrict__ wte,
                   float* __restrict__ out)
{
    __shared__ float xs[2 * Cc];
    int tid = threadIdx.x;
    for (int l = tid; l < 2 * Cc; l += 256) xs[l] = xf[l];
    __syncthreads();
    int w = tid >> 6, lane = tid & 63;
    int vrow = blockIdx.x * 4 + w;
    const float* wr = wte + (size_t)vrow * Cc;
    float a0 = 0.f, a1 = 0.f;
    for (int k = lane; k < Cc; k += 64) {
        float wv = wr[k];
        a0 += wv * xs[k];
        a1 += wv * xs[Cc + k];
    }
    for (int o = 32; o; o >>= 1) {
        a0 += __shfl_down(a0, o);
        a1 += __shfl_down(a1, o);
    }
    if (lane == 0) {
        out[vrow] = a0;
        out[Vc + vrow] = a1;
    }
}

// ==========================================================================
extern "C" void kernel_launch(void* const* d_in, const int* in_sizes, int n_in,
                              void* d_out, int out_size, void* d_ws, size_t ws_size,
                              hipStream_t stream)
{
    const int*   idx        = (const int*)  d_in[0];
    const float* wte        = (const float*)d_in[1];
    const float* wpe        = (const float*)d_in[2];
    const float* attn_ln_w  = (const float*)d_in[3];
    const float* attn_ln_b  = (const float*)d_in[4];
    const float* c_attn_w   = (const float*)d_in[5];   // [769, 2304]
    const float* c_attn_b   = (const float*)d_in[6];
    const float* c_proj_w   = (const float*)d_in[7];   // [768, 768]
    const float* c_proj_b   = (const float*)d_in[8];
    const float* mlp_ln_w   = (const float*)d_in[9];
    const float* mlp_ln_b   = (const float*)d_in[10];
    const float* c_fc_w     = (const float*)d_in[11];  // [769, 3072]
    const float* c_fc_b     = (const float*)d_in[12];
    const float* mlp_proj_w = (const float*)d_in[13];  // [3072, 768]
    const float* mlp_proj_b = (const float*)d_in[14];
    const float* lnf_w      = (const float*)d_in[15];
    const float* lnf_b      = (const float*)d_in[16];
    float* out = (float*)d_out;

    // workspace layout (fp32)
    float* ws = (float*)d_ws;
    size_t off = 0;
    auto alloc = [&](size_t n) { float* p = ws + off; off += n; return p; };
    float* z    = alloc((size_t)BTc * Cc);        // 3 MB
    float* xln  = alloc((size_t)BTc * Cc);        // LN out; later aliased as y
    float* xt   = alloc(BTc);                     // LN'd time column
    float* qkv  = alloc((size_t)BTc * C3);        // 9 MB
    float* att  = alloc((size_t)NHc * Tc * Tc);   // 25 MB: S -> att -> h1 alias
    float* attT = alloc((size_t)NHc * Tc * Tc);   // 25 MB: att^T -> pi alias
    float* u    = alloc(NHc * Tc);
    float* v    = alloc(NHc * Tc);                // contiguous after u
    float* ao   = alloc((size_t)BTc * Cc);        // attn out
    float* xf   = alloc(2 * Cc);                  // final LN (last rows)
    float* y  = xln;    // pi@v output reuses xln (free after qkv GEMM)
    float* pi = attT;   // transport plan reuses attT (free after last v-pass)
    float* h1 = att;    // fc activation reuses att (free after pi_kernel)

    // z = wte[idx] + wpe
    embed_kernel<<<(BTc * Cc + 255) / 256, 256, 0, stream>>>(idx, wte, wpe, z);

    float t = 0.f;
    for (int step = 0; step < 20; ++step) {
        // --- attention sub-block ---
        ln_kernel<<<BTc, 256, 0, stream>>>(z, attn_ln_w, attn_ln_b, xln, xt, 1, t, 1, 0);
        gemm_nn<0><<<dim3(C3 / 64, BTc / 64), 256, 0, stream>>>(
            xln, Cc, c_attn_w, C3, qkv, C3, BTc, C3, Cc,
            c_attn_b, xt, c_attn_w + (size_t)Cc * C3, 0.f);
        qk_kernel<<<dim3(8, 8, NHc), 256, 0, stream>>>(qkv, att);
        softmax_causal<<<NHc * Tc, 256, 0, stream>>>(att);
        transpose512<<<dim3(16, 16, NHc), 256, 0, stream>>>(att, attT);
        // --- Sinkhorn (6 iters, log domain) ---
        zero_kernel<<<(2 * NHc * Tc + 255) / 256, 256, 0, stream>>>(u, 2 * NHc * Tc);
        for (int it = 0; it < 6; ++it) {
            sink_pass<<<NHc * Tc, 256, 0, stream>>>(att, v, u);    // u update
            sink_pass<<<NHc * Tc, 256, 0, stream>>>(attT, u, v);   // v update
        }
        pi_kernel<<<NHc * Tc * Tc / 256, 256, 0, stream>>>(att, u, v, pi);
        piv_kernel<<<dim3(8, NHc), 256, 0, stream>>>(pi, qkv, y);
        gemm_nn<0><<<dim3(Cc / 64, BTc / 64), 256, 0, stream>>>(
            y, Cc, c_proj_w, Cc, ao, Cc, BTc, Cc, Cc,
            c_proj_b, nullptr, nullptr, 0.f);
        // --- MLP sub-block ---
        ln_kernel<<<BTc, 256, 0, stream>>>(ao, mlp_ln_w, mlp_ln_b, xln, xt, 1, t, 1, 0);
        gemm_nn<1><<<dim3(C4 / 64, BTc / 64), 256, 0, stream>>>(
            xln, Cc, c_fc_w, C4, h1, C4, BTc, C4, Cc,
            c_fc_b, xt, c_fc_w + (size_t)Cc * C4, 0.f);
        gemm_nn<2><<<dim3(Cc / 64, BTc / 64), 256, 0, stream>>>(
            h1, C4, mlp_proj_w, Cc, z, Cc, BTc, Cc, C4,
            mlp_proj_b, nullptr, nullptr, H_STEP);
        t += H_STEP;
    }

    // final LN on last position of each batch, then tied-head logits
    ln_kernel<<<2, 256, 0, stream>>>(z, lnf_w, lnf_b, xf, nullptr, 0, 0.f, Tc, Tc - 1);
    logits_kernel<<<Vc / 4, 256, 0, stream>>>(xf, wte, out);
}

// Round 2
// 7672.633 us; speedup vs baseline: 2.8857x; 2.8857x over previous
//
#include <hip/hip_runtime.h>
#include <hip/hip_bf16.h>
#include <math.h>

typedef unsigned short ushortT;

// Problem constants
#define Bc   2
#define Tc   512
#define Cc   768
#define Hc   12
#define HDc  64
#define Vc   50304
#define BTc  (Bc*Tc)          // 1024
#define NHc  (Bc*Hc)          // 24
#define C3   (3*Cc)           // 2304
#define C4   (4*Cc)           // 3072
#define EPS_LN 1e-5f
#define H_STEP 0.05f
#define LOGMARG (-6.2383246250395077847550890931236f)  // -log(512)

typedef float f32x4 __attribute__((ext_vector_type(4)));
typedef __bf16 bf16x8 __attribute__((ext_vector_type(8)));

// ---------------- bf16 helpers --------------------------------------------
__device__ __forceinline__ ushortT f2bf(float f) {
    union { float f; unsigned u; } x; x.f = f;
    unsigned r = (x.u + 0x7fffu + ((x.u >> 16) & 1u)) >> 16;
    return (ushortT)r;
}
__device__ __forceinline__ float bf2f(ushortT b) {
    union { unsigned u; float f; } x; x.u = ((unsigned)b) << 16;
    return x.f;
}

// async global->LDS, 16 bytes per lane
__device__ __forceinline__ void gll16(const ushortT* g, ushortT* l) {
    __builtin_amdgcn_global_load_lds(
        (const __attribute__((address_space(1))) unsigned int*)g,
        (__attribute__((address_space(3))) unsigned int*)l,
        16, 0, 0);
}

// ---------------- block reductions (256 threads = 4 waves of 64) ----------
__device__ __forceinline__ float waveReduceMax(float v) {
    for (int o = 32; o; o >>= 1) v = fmaxf(v, __shfl_down(v, o));
    return v;
}
__device__ __forceinline__ float waveReduceSum(float v) {
    for (int o = 32; o; o >>= 1) v += __shfl_down(v, o);
    return v;
}
__device__ __forceinline__ float blockReduceMax(float v) {
    __shared__ float sm[4];
    v = waveReduceMax(v);
    __syncthreads();
    if ((threadIdx.x & 63) == 0) sm[threadIdx.x >> 6] = v;
    __syncthreads();
    return fmaxf(fmaxf(sm[0], sm[1]), fmaxf(sm[2], sm[3]));
}
__device__ __forceinline__ float blockReduceSum(float v) {
    __shared__ float sm[4];
    v = waveReduceSum(v);
    __syncthreads();
    if ((threadIdx.x & 63) == 0) sm[threadIdx.x >> 6] = v;
    __syncthreads();
    return sm[0] + sm[1] + sm[2] + sm[3];
}

// ---------------- embedding: z = wte[idx] + wpe[t] ------------------------
__global__ __launch_bounds__(256)
void embed_kernel(const int* __restrict__ idx, const float* __restrict__ wte,
                  const float* __restrict__ wpe, float* __restrict__ z)
{
    int i = blockIdx.x * 256 + threadIdx.x;
    if (i >= BTc * Cc) return;
    int r = i / Cc, c = i - r * Cc;
    int tok = idx[r];
    z[i] = wte[(size_t)tok * Cc + c] + wpe[(size_t)(r & (Tc - 1)) * Cc + c];
}

// ---------------- weight fp32 [K][N] -> bf16 [N][K] transpose -------------
__global__ __launch_bounds__(256)
void wtrans_kernel(const float* __restrict__ W, ushortT* __restrict__ out,
                   int K, int N)
{
    __shared__ float t[32][33];
    int k0 = blockIdx.x * 32, n0 = blockIdx.y * 32;
    int tx = threadIdx.x & 31, ty = threadIdx.x >> 5;
    for (int r = ty; r < 32; r += 8)
        t[r][tx] = W[(size_t)(k0 + r) * N + n0 + tx];
    __syncthreads();
    for (int r = ty; r < 32; r += 8)
        out[(size_t)(n0 + r) * K + k0 + tx] = f2bf(t[tx][r]);
}

// ---------------- v-part of qkv (bf16) -> vT [NH][64][512] ----------------
__global__ __launch_bounds__(256)
void vtrans_kernel(const ushortT* __restrict__ qkv, ushortT* __restrict__ vT)
{
    __shared__ ushortT t[32][33];
    int n = blockIdx.z; int b = n / Hc, h = n - b * Hc;
    int t0 = blockIdx.x * 32, d0 = blockIdx.y * 32;
    int tx = threadIdx.x & 31, ty = threadIdx.x >> 5;
    const ushortT* src = qkv + (size_t)(b * Tc) * C3 + 2 * Cc + h * HDc;
    for (int r = ty; r < 32; r += 8)
        t[r][tx] = src[(size_t)(t0 + r) * C3 + d0 + tx];
    __syncthreads();
    ushortT* dst = vT + (size_t)n * HDc * Tc;
    for (int r = ty; r < 32; r += 8)
        dst[(size_t)(d0 + r) * Tc + t0 + tx] = t[tx][r];
}

// ---------------- LayerNorm over 768 dims (+optional time column) ---------
__global__ __launch_bounds__(256)
void ln_kernel(const float* __restrict__ X, const float* __restrict__ w,
               const float* __restrict__ bb, void* __restrict__ Y,
               float* __restrict__ yt, int hasT, float tval,
               int rowMul, int rowAdd, int obf16)
{
    int orow = blockIdx.x;
    int r = orow * rowMul + rowAdd;
    const float* x = X + (size_t)r * Cc;
    int tid = threadIdx.x;
    float xv[3];
#pragma unroll
    for (int q = 0; q < 3; ++q) xv[q] = x[tid + 256 * q];
    float s = xv[0] + xv[1] + xv[2];
    s = blockReduceSum(s);
    float cnt = hasT ? (float)(Cc + 1) : (float)Cc;
    float mu = (s + (hasT ? tval : 0.f)) / cnt;
    float d0 = xv[0] - mu, d1 = xv[1] - mu, d2 = xv[2] - mu;
    float ss = d0 * d0 + d1 * d1 + d2 * d2;
    ss = blockReduceSum(ss);
    float dt = tval - mu;
    float var = (ss + (hasT ? dt * dt : 0.f)) / cnt;
    float rs = rsqrtf(var + EPS_LN);
#pragma unroll
    for (int q = 0; q < 3; ++q) {
        int c = tid + 256 * q;
        float v = (xv[q] - mu) * rs * w[c] + bb[c];
        if (obf16) ((ushortT*)Y)[(size_t)orow * Cc + c] = f2bf(v);
        else       ((float*)Y)[(size_t)orow * Cc + c] = v;
    }
    if (hasT && tid == 0) yt[orow] = dt * rs * w[Cc] + bb[Cc];
}

// ---------------- MFMA GEMM: C = A[M,K](bf16) @ Bt[N,K](bf16)^T -----------
// 128x128 tile, BK=32, 4 waves (2x2), each wave 64x64 = 4x4 mfma frags.
// EPI: 0 = bias(+rank1) -> bf16 ; 1 = gelu(bias+rank1) -> bf16 ;
//      2 = z += h*(acc+bias) fp32 ; 3 = bias -> fp32
template <int EPI>
__global__ __launch_bounds__(256)
void gemm_bt(const ushortT* __restrict__ A, int lda,
             const ushortT* __restrict__ Bt, int ldb,
             void* __restrict__ Cm, int ldc, int K,
             const float* __restrict__ bias,
             const float* __restrict__ extraA,
             const float* __restrict__ extraB)
{
    __shared__ __align__(16) ushortT Als[128][32];
    __shared__ __align__(16) ushortT Bls[128][32];
    int tid = threadIdx.x;
    int lane = tid & 63, wid = tid >> 6;
    int wm = wid >> 1, wn = wid & 1;
    int m0 = blockIdx.y * 128, n0 = blockIdx.x * 128;
    f32x4 acc[4][4];
    const f32x4 fz = {0.f, 0.f, 0.f, 0.f};
#pragma unroll
    for (int i = 0; i < 4; ++i)
#pragma unroll
        for (int j = 0; j < 4; ++j) acc[i][j] = fz;

    for (int k0 = 0; k0 < K; k0 += 32) {
#pragma unroll
        for (int is = 0; is < 2; ++is) {
            int ch = is * 256 + tid;            // 0..511
            int m = ch >> 2, kc = ch & 3;
            gll16(A + (size_t)(m0 + m) * lda + k0 + kc * 8, &Als[0][0] + ch * 8);
            gll16(Bt + (size_t)(n0 + m) * ldb + k0 + kc * 8, &Bls[0][0] + ch * 8);
        }
        __syncthreads();
        bf16x8 af[4], bfv[4];
#pragma unroll
        for (int i = 0; i < 4; ++i) {
            int row = wm * 64 + i * 16 + (lane & 15);
            af[i] = *(const bf16x8*)&Als[row][(lane >> 4) * 8];
            int col = wn * 64 + i * 16 + (lane & 15);
            bfv[i] = *(const bf16x8*)&Bls[col][(lane >> 4) * 8];
        }
#pragma unroll
        for (int i = 0; i < 4; ++i)
#pragma unroll
            for (int j = 0; j < 4; ++j)
                acc[i][j] = __builtin_amdgcn_mfma_f32_16x16x32_bf16(af[i], bfv[j], acc[i][j], 0, 0, 0);
        __syncthreads();
    }
#pragma unroll
    for (int i = 0; i < 4; ++i) {
#pragma unroll
        for (int j = 0; j < 4; ++j) {
#pragma unroll
            for (int r = 0; r < 4; ++r) {
                int row = m0 + wm * 64 + i * 16 + (lane >> 4) * 4 + r;
                int col = n0 + wn * 64 + j * 16 + (lane & 15);
                float v = acc[i][j][r];
                if (extraA) v += extraA[row] * extraB[col];
                if (bias) v += bias[col];
                size_t oi = (size_t)row * ldc + col;
                if (EPI == 0) {
                    ((ushortT*)Cm)[oi] = f2bf(v);
                } else if (EPI == 1) {
                    v = 0.5f * v * (1.f + erff(v * 0.70710678118654752440f));
                    ((ushortT*)Cm)[oi] = f2bf(v);
                } else if (EPI == 2) {
                    float* Z = (float*)Cm;
                    Z[oi] = Z[oi] + H_STEP * v;
                } else {
                    ((float*)Cm)[oi] = v;
                }
            }
        }
    }
}

// ---------------- QK^T via MFMA: S = q@k^T / 8 (fp32 out), causal skip ----
__global__ __launch_bounds__(256)
void qk_mfma(const ushortT* __restrict__ qkv, float* __restrict__ S)
{
    int n = blockIdx.z; int b = n / Hc, h = n - b * Hc;
    int m0 = blockIdx.y * 128, n0 = blockIdx.x * 128;
    if (n0 > m0 + 127) return;                 // fully-masked tile
    const ushortT* Aq = qkv + (size_t)(b * Tc) * C3 + h * HDc;
    const ushortT* Bk = Aq + Cc;
    __shared__ __align__(16) ushortT Als[128][32];
    __shared__ __align__(16) ushortT Bls[128][32];
    int tid = threadIdx.x;
    int lane = tid & 63, wid = tid >> 6;
    int wm = wid >> 1, wn = wid & 1;
    f32x4 acc[4][4];
    const f32x4 fz = {0.f, 0.f, 0.f, 0.f};
#pragma unroll
    for (int i = 0; i < 4; ++i)
#pragma unroll
        for (int j = 0; j < 4; ++j) acc[i][j] = fz;

    for (int k0 = 0; k0 < HDc; k0 += 32) {
#pragma unroll
        for (int is = 0; is < 2; ++is) {
            int ch = is * 256 + tid;
            int m = ch >> 2, kc = ch & 3;
            gll16(Aq + (size_t)(m0 + m) * C3 + k0 + kc * 8, &Als[0][0] + ch * 8);
            gll16(Bk + (size_t)(n0 + m) * C3 + k0 + kc * 8, &Bls[0][0] + ch * 8);
        }
        __syncthreads();
        bf16x8 af[4], bfv[4];
#pragma unroll
        for (int i = 0; i < 4; ++i) {
            int row = wm * 64 + i * 16 + (lane & 15);
            af[i] = *(const bf16x8*)&Als[row][(lane >> 4) * 8];
            int col = wn * 64 + i * 16 + (lane & 15);
            bfv[i] = *(const bf16x8*)&Bls[col][(lane >> 4) * 8];
        }
#pragma unroll
        for (int i = 0; i < 4; ++i)
#pragma unroll
            for (int j = 0; j < 4; ++j)
                acc[i][j] = __builtin_amdgcn_mfma_f32_16x16x32_bf16(af[i], bfv[j], acc[i][j], 0, 0, 0);
        __syncthreads();
    }
    float* Sb = S + (size_t)n * Tc * Tc;
#pragma unroll
    for (int i = 0; i < 4; ++i)
#pragma unroll
        for (int j = 0; j < 4; ++j)
#pragma unroll
            for (int r = 0; r < 4; ++r) {
                int row = m0 + wm * 64 + i * 16 + (lane >> 4) * 4 + r;
                int col = n0 + wn * 64 + j * 16 + (lane & 15);
                Sb[(size_t)row * Tc + col] = acc[i][j][r] * 0.125f;
            }
}

// ---------------- pi @ v via MFMA: y[b,t,h*64+d] (bf16 out) ---------------
__global__ __launch_bounds__(256)
void piv_mfma(const ushortT* __restrict__ pi, const ushortT* __restrict__ vT,
              ushortT* __restrict__ y)
{
    int n = blockIdx.y; int b = n / Hc, h = n - b * Hc;
    int m0 = blockIdx.x * 128;
    const ushortT* Ap = pi + (size_t)n * Tc * Tc;    // lda=512
    const ushortT* Bv = vT + (size_t)n * HDc * Tc;   // ldb=512
    __shared__ __align__(16) ushortT Als[128][32];
    __shared__ __align__(16) ushortT Bls[64][32];
    int tid = threadIdx.x;
    int lane = tid & 63, wid = tid >> 6;
    int wm = wid >> 1, wn = wid & 1;
    f32x4 acc[4][2];
    const f32x4 fz = {0.f, 0.f, 0.f, 0.f};
#pragma unroll
    for (int i = 0; i < 4; ++i)
#pragma unroll
        for (int j = 0; j < 2; ++j) acc[i][j] = fz;

    for (int k0 = 0; k0 < Tc; k0 += 32) {
#pragma unroll
        for (int is = 0; is < 2; ++is) {
            int ch = is * 256 + tid;
            int m = ch >> 2, kc = ch & 3;
            gll16(Ap + (size_t)(m0 + m) * Tc + k0 + kc * 8, &Als[0][0] + ch * 8);
        }
        {
            int ch = tid;                       // 64 rows * 4 chunks
            int d = ch >> 2, kc = ch & 3;
            gll16(Bv + (size_t)d * Tc + k0 + kc * 8, &Bls[0][0] + ch * 8);
        }
        __syncthreads();
        bf16x8 af[4], bfv[2];
#pragma unroll
        for (int i = 0; i < 4; ++i) {
            int row = wm * 64 + i * 16 + (lane & 15);
            af[i] = *(const bf16x8*)&Als[row][(lane >> 4) * 8];
        }
#pragma unroll
        for (int j = 0; j < 2; ++j) {
            int col = wn * 32 + j * 16 + (lane & 15);
            bfv[j] = *(const bf16x8*)&Bls[col][(lane >> 4) * 8];
        }
#pragma unroll
        for (int i = 0; i < 4; ++i)
#pragma unroll
            for (int j = 0; j < 2; ++j)
                acc[i][j] = __builtin_amdgcn_mfma_f32_16x16x32_bf16(af[i], bfv[j], acc[i][j], 0, 0, 0);
        __syncthreads();
    }
#pragma unroll
    for (int i = 0; i < 4; ++i)
#pragma unroll
        for (int j = 0; j < 2; ++j)
#pragma unroll
            for (int r = 0; r < 4; ++r) {
                int row = b * Tc + m0 + wm * 64 + i * 16 + (lane >> 4) * 4 + r;
                int col = h * HDc + wn * 32 + j * 16 + (lane & 15);
                y[(size_t)row * Cc + col] = f2bf(acc[i][j][r]);
            }
}

// ---------------- causal softmax, in place ---------------------------------
__global__ __launch_bounds__(256)
void softmax_causal(float* __restrict__ S)
{
    int rw = blockIdx.x;
    int i = rw & (Tc - 1);
    float* row = S + (size_t)rw * Tc;
    int tid = threadIdx.x;
    int j0 = tid, j1 = tid + 256;
    float x0 = (j0 <= i) ? row[j0] : -INFINITY;
    float x1 = (j1 <= i) ? row[j1] : -INFINITY;
    float mx = blockReduceMax(fmaxf(x0, x1));
    float e0 = (j0 <= i) ? expf(x0 - mx) : 0.f;
    float e1 = (j1 <= i) ? expf(x1 - mx) : 0.f;
    float s = blockReduceSum(e0 + e1);
    float inv = 1.f / s;
    row[j0] = e0 * inv;
    row[j1] = e1 * inv;
}

// ---------------- 512x512 fp32 transpose per head -------------------------
__global__ __launch_bounds__(256)
void transpose512(const float* __restrict__ A, float* __restrict__ At)
{
    __shared__ float tile[32][33];
    int n = blockIdx.z;
    int i0 = blockIdx.y * 32, j0 = blockIdx.x * 32;
    const float* Ab = A + (size_t)n * Tc * Tc;
    float* Atb = At + (size_t)n * Tc * Tc;
    int tx = threadIdx.x & 31, ty = threadIdx.x >> 5;
    for (int r = ty; r < 32; r += 8)
        tile[r][tx] = Ab[(size_t)(i0 + r) * Tc + (j0 + tx)];
    __syncthreads();
    for (int r = ty; r < 32; r += 8)
        Atb[(size_t)(j0 + r) * Tc + (i0 + tx)] = tile[tx][r];
}

__global__ void zero_kernel(float* __restrict__ p, int n)
{
    int i = blockIdx.x * 256 + threadIdx.x;
    if (i < n) p[i] = 0.f;
}

// ---------------- one Sinkhorn half-iteration (fp32) ----------------------
__global__ __launch_bounds__(256)
void sink_pass(const float* __restrict__ Cmat, const float* __restrict__ vin,
               float* __restrict__ uout)
{
    int rw = blockIdx.x;
    int n = rw >> 9;
    const float* row = Cmat + (size_t)rw * Tc;
    const float* vv = vin + n * Tc;
    int tid = threadIdx.x;
    float x0 = -row[tid] + vv[tid];
    float x1 = -row[tid + 256] + vv[tid + 256];
    float mx = blockReduceMax(fmaxf(x0, x1));
    float s = blockReduceSum(expf(x0 - mx) + expf(x1 - mx));
    if (tid == 0) uout[rw] = LOGMARG - (mx + logf(s));
}

// ---------------- pi = exp(-C + u_i + v_j) * T  (bf16 out) ----------------
__global__ __launch_bounds__(256)
void pi_kernel(const float* __restrict__ Cmat, const float* __restrict__ u,
               const float* __restrict__ v, ushortT* __restrict__ pi)
{
    int idx = blockIdx.x * 256 + threadIdx.x;
    int j = idx & (Tc - 1);
    int i = (idx >> 9) & (Tc - 1);
    int n = idx >> 18;
    pi[idx] = f2bf(expf(-Cmat[idx] + u[n * Tc + i] + v[n * Tc + j]) * (float)Tc);
}

// ---------------- logits: out[b,v] = xf[b,:] . wte[v,:] (fp32) ------------
__global__ __launch_bounds__(256)
void logits_kernel(const float* __restrict__ xf, const float* __restrict__ wte,
                   float* __restrict__ out)
{
    __shared__ float xs[2 * Cc];
    int tid = threadIdx.x;
    for (int l = tid; l < 2 * Cc; l += 256) xs[l] = xf[l];
    __syncthreads();
    int w = tid >> 6, lane = tid & 63;
    int vrow = blockIdx.x * 4 + w;
    const float* wr = wte + (size_t)vrow * Cc;
    float a0 = 0.f, a1 = 0.f;
    for (int k = lane; k < Cc; k += 64) {
        float wv = wr[k];
        a0 += wv * xs[k];
        a1 += wv * xs[Cc + k];
    }
    for (int o = 32; o; o >>= 1) {
        a0 += __shfl_down(a0, o);
        a1 += __shfl_down(a1, o);
    }
    if (lane == 0) {
        out[vrow] = a0;
        out[Vc + vrow] = a1;
    }
}

// ==========================================================================
extern "C" void kernel_launch(void* const* d_in, const int* in_sizes, int n_in,
                              void* d_out, int out_size, void* d_ws, size_t ws_size,
                              hipStream_t stream)
{
    const int*   idx        = (const int*)  d_in[0];
    const float* wte        = (const float*)d_in[1];
    const float* wpe        = (const float*)d_in[2];
    const float* attn_ln_w  = (const float*)d_in[3];
    const float* attn_ln_b  = (const float*)d_in[4];
    const float* c_attn_w   = (const float*)d_in[5];   // [769, 2304]
    const float* c_attn_b   = (const float*)d_in[6];
    const float* c_proj_w   = (const float*)d_in[7];   // [768, 768]
    const float* c_proj_b   = (const float*)d_in[8];
    const float* mlp_ln_w   = (const float*)d_in[9];
    const float* mlp_ln_b   = (const float*)d_in[10];
    const float* c_fc_w     = (const float*)d_in[11];  // [769, 3072]
    const float* c_fc_b     = (const float*)d_in[12];
    const float* mlp_proj_w = (const float*)d_in[13];  // [3072, 768]
    const float* mlp_proj_b = (const float*)d_in[14];
    const float* lnf_w      = (const float*)d_in[15];
    const float* lnf_b      = (const float*)d_in[16];
    float* out = (float*)d_out;

    // -------- workspace carving (256B aligned blocks) --------
    char* base = (char*)d_ws;
    size_t off = 0;
    auto alloc = [&](size_t bytes) -> void* {
        void* p = base + off;
        off = (off + bytes + 255) & ~(size_t)255;
        return p;
    };
    float*   z     = (float*)  alloc((size_t)BTc * Cc * 4);
    float*   ao    = (float*)  alloc((size_t)BTc * Cc * 4);
    float*   att   = (float*)  alloc((size_t)NHc * Tc * Tc * 4);   // S / att; h1 aliases
    float*   attT  = (float*)  alloc((size_t)NHc * Tc * Tc * 4);   // att^T; pi aliases
    ushortT* qkvb  = (ushortT*)alloc((size_t)BTc * C3 * 2);
    ushortT* xlnb  = (ushortT*)alloc((size_t)BTc * Cc * 2);
    ushortT* y     = (ushortT*)alloc((size_t)BTc * Cc * 2);
    ushortT* vT    = (ushortT*)alloc((size_t)NHc * HDc * Tc * 2);
    float*   xt    = (float*)  alloc(BTc * 4);
    float*   u     = (float*)  alloc(NHc * Tc * 4);
    float*   v     = (float*)  alloc(NHc * Tc * 4);   // contiguous after u
    float*   xf    = (float*)  alloc(2 * Cc * 4);
    ushortT* WqkvT = (ushortT*)alloc((size_t)C3 * Cc * 2);
    ushortT* WprojT= (ushortT*)alloc((size_t)Cc * Cc * 2);
    ushortT* WfcT  = (ushortT*)alloc((size_t)C4 * Cc * 2);
    ushortT* WmlpT = (ushortT*)alloc((size_t)Cc * C4 * 2);
    ushortT* h1  = (ushortT*)att;   // [BTc][C4] bf16, alias (att dead after pi_kernel)
    ushortT* pib = (ushortT*)attT;  // [NH][T][T] bf16, alias (attT dead after sinkhorn)

    // -------- once-per-launch: embedding + weight convert/transpose --------
    embed_kernel<<<(BTc * Cc + 255) / 256, 256, 0, stream>>>(idx, wte, wpe, z);
    wtrans_kernel<<<dim3(Cc / 32, C3 / 32), 256, 0, stream>>>(c_attn_w,   WqkvT,  Cc, C3);
    wtrans_kernel<<<dim3(Cc / 32, Cc / 32), 256, 0, stream>>>(c_proj_w,   WprojT, Cc, Cc);
    wtrans_kernel<<<dim3(Cc / 32, C4 / 32), 256, 0, stream>>>(c_fc_w,     WfcT,   Cc, C4);
    wtrans_kernel<<<dim3(C4 / 32, Cc / 32), 256, 0, stream>>>(mlp_proj_w, WmlpT,  C4, Cc);

    float t = 0.f;
    for (int step = 0; step < 20; ++step) {
        // --- attention sub-block ---
        ln_kernel<<<BTc, 256, 0, stream>>>(z, attn_ln_w, attn_ln_b, xlnb, xt, 1, t, 1, 0, 1);
        gemm_bt<0><<<dim3(C3 / 128, BTc / 128), 256, 0, stream>>>(
            xlnb, Cc, WqkvT, Cc, qkvb, C3, Cc,
            c_attn_b, xt, c_attn_w + (size_t)Cc * C3);
        vtrans_kernel<<<dim3(Tc / 32, HDc / 32, NHc), 256, 0, stream>>>(qkvb, vT);
        qk_mfma<<<dim3(Tc / 128, Tc / 128, NHc), 256, 0, stream>>>(qkvb, att);
        softmax_causal<<<NHc * Tc, 256, 0, stream>>>(att);
        transpose512<<<dim3(16, 16, NHc), 256, 0, stream>>>(att, attT);
        // --- Sinkhorn (6 iters, log domain, fp32) ---
        zero_kernel<<<(2 * NHc * Tc + 255) / 256, 256, 0, stream>>>(u, 2 * NHc * Tc);
        for (int it = 0; it < 6; ++it) {
            sink_pass<<<NHc * Tc, 256, 0, stream>>>(att, v, u);    // u update
            sink_pass<<<NHc * Tc, 256, 0, stream>>>(attT, u, v);   // v update
        }
        pi_kernel<<<NHc * Tc * Tc / 256, 256, 0, stream>>>(att, u, v, pib);
        piv_mfma<<<dim3(Tc / 128, NHc), 256, 0, stream>>>(pib, vT, y);
        gemm_bt<3><<<dim3(Cc / 128, BTc / 128), 256, 0, stream>>>(
            y, Cc, WprojT, Cc, ao, Cc, Cc,
            c_proj_b, nullptr, nullptr);
        // --- MLP sub-block ---
        ln_kernel<<<BTc, 256, 0, stream>>>(ao, mlp_ln_w, mlp_ln_b, xlnb, xt, 1, t, 1, 0, 1);
        gemm_bt<1><<<dim3(C4 / 128, BTc / 128), 256, 0, stream>>>(
            xlnb, Cc, WfcT, Cc, h1, C4, Cc,
            c_fc_b, xt, c_fc_w + (size_t)Cc * C4);
        gemm_bt<2><<<dim3(Cc / 128, BTc / 128), 256, 0, stream>>>(
            h1, C4, WmlpT, C4, z, Cc, C4,
            mlp_proj_b, nullptr, nullptr);
        t += H_STEP;
    }

    // final LN on last position of each batch, then tied-head logits (fp32)
    ln_kernel<<<2, 256, 0, stream>>>(z, lnf_w, lnf_b, xf, nullptr, 0, 0.f, Tc, Tc - 1, 0);
    logits_kernel<<<Vc / 4, 256, 0, stream>>>(xf, wte, out);
}